// Round 2
// baseline (1977.301 us; speedup 1.0000x reference)
//
#include <hip/hip_runtime.h>
#include <hip/hip_bf16.h>
#include <math.h>

// Problem constants
#define B   64
#define S   256
#define DD  512
#define H   8
#define DH  64
#define BH  (B*H)   // 512

// ---------------------------------------------------------------------------
// K1: QKV projections.  X(16384x512) @ W(512x512) for z in {q,k,v}.
// Output layout (B,H,S,DH) so per-(b,h) tiles are contiguous.
// ---------------------------------------------------------------------------
__global__ __launch_bounds__(256) void gemm_qkv_kernel(
    const float* __restrict__ x,
    const float* __restrict__ wq, const float* __restrict__ wk, const float* __restrict__ wv,
    float* __restrict__ qo, float* __restrict__ ko, float* __restrict__ vo)
{
    const int zid = blockIdx.z;
    const float* w = (zid == 0) ? wq : (zid == 1) ? wk : wv;
    float* dst     = (zid == 0) ? qo : (zid == 1) ? ko : vo;

    const int row0 = blockIdx.y * 64;
    const int col0 = blockIdx.x * 64;

    __shared__ float As[16][68];   // transposed A tile [k][row], pad to 68
    __shared__ float Bs[16][64];   // [k][col]

    const int tid = threadIdx.x;
    const int tx = tid & 15, ty = tid >> 4;

    float acc[4][4] = {};

    for (int k0 = 0; k0 < DD; k0 += 16) {
        {
            const int kk = tid & 15;
            const int rb = tid >> 4;
            #pragma unroll
            for (int it = 0; it < 4; ++it) {
                const int rr = rb + 16 * it;
                As[kk][rr] = x[(size_t)(row0 + rr) * DD + k0 + kk];
            }
            const int cc = tid & 63;
            const int kb = tid >> 6;
            #pragma unroll
            for (int it = 0; it < 4; ++it) {
                const int kk2 = kb + 4 * it;
                Bs[kk2][cc] = w[(size_t)(k0 + kk2) * DD + col0 + cc];
            }
        }
        __syncthreads();
        #pragma unroll
        for (int kk = 0; kk < 16; ++kk) {
            const float4 a4 = *(const float4*)&As[kk][ty * 4];
            const float4 b4 = *(const float4*)&Bs[kk][tx * 4];
            const float av[4] = {a4.x, a4.y, a4.z, a4.w};
            const float bv[4] = {b4.x, b4.y, b4.z, b4.w};
            #pragma unroll
            for (int i2 = 0; i2 < 4; ++i2)
                #pragma unroll
                for (int j2 = 0; j2 < 4; ++j2)
                    acc[i2][j2] += av[i2] * bv[j2];
        }
        __syncthreads();
    }

    #pragma unroll
    for (int i2 = 0; i2 < 4; ++i2) {
        const int row = row0 + ty * 4 + i2;
        const int bb = row >> 8, ss = row & 255;
        #pragma unroll
        for (int j2 = 0; j2 < 4; ++j2) {
            const int c = col0 + tx * 4 + j2;
            const int hh = c >> 6, dd = c & 63;
            dst[(((size_t)(bb * H + hh)) * S + ss) * DH + dd] = acc[i2][j2];
        }
    }
}

// ---------------------------------------------------------------------------
// K2: pairwise features + tiny MLP -> m[b][i][j]  (B,S,S) f32
// ---------------------------------------------------------------------------
__global__ __launch_bounds__(256) void pairwise_mlp_kernel(
    const float* __restrict__ particles,
    const float* __restrict__ mw1, const float* __restrict__ mb1,
    const float* __restrict__ mw2, const float* __restrict__ mb2,
    const float* __restrict__ mw3, const float* __restrict__ mb3,
    float* __restrict__ mbuf)
{
    __shared__ float w1[32], b1[8], w2[64], b2[8], w3[8];
    __shared__ float b3s;
    const int tid = threadIdx.x;
    if (tid < 32)                 w1[tid]        = mw1[tid];
    if (tid >= 32 && tid < 40)    b1[tid - 32]   = mb1[tid - 32];
    if (tid >= 64 && tid < 128)   w2[tid - 64]   = mw2[tid - 64];
    if (tid >= 128 && tid < 136)  b2[tid - 128]  = mb2[tid - 128];
    if (tid >= 136 && tid < 144)  w3[tid - 136]  = mw3[tid - 136];
    if (tid == 144)               b3s            = mb3[0];

    const int bi = blockIdx.x;            // b*S + i
    const int bb = bi >> 8;
    const float pt_i  = particles[(size_t)bi * 3 + 0];
    const float eta_i = particles[(size_t)bi * 3 + 1];
    const float phi_i = particles[(size_t)bi * 3 + 2];

    const int j = tid;
    const float* pj = particles + ((size_t)(bb * S) + j) * 3;
    const float pt_j = pj[0], eta_j = pj[1], phi_j = pj[2];

    __syncthreads();

    const float d_eta = eta_i - eta_j;
    const float dp    = phi_i - phi_j;
    const float d_phi = atan2f(sinf(dp), cosf(dp));      // wrap to [-pi,pi]
    const float delta = sqrtf(d_eta * d_eta + d_phi * d_phi);
    const float min_pt = fminf(pt_i, pt_j);
    const float kT = min_pt * delta;
    const float zf = min_pt / (pt_i + pt_j + 1e-8f);
    const float cd = cosf(d_phi);                        // cos of the WRAPPED angle
    const float m2 = fmaxf(pt_i * pt_i + pt_j * pt_j - 2.0f * pt_i * pt_j * cd, 1e-8f);

    const float eps = 1e-8f;
    const float f[4] = { logf(fmaxf(delta, eps)),
                         logf(fmaxf(kT,    eps)),
                         logf(fmaxf(zf,    eps)),
                         logf(m2) };

    float h1[8];
    #pragma unroll
    for (int o = 0; o < 8; ++o) {
        float s = b1[o];
        #pragma unroll
        for (int i4 = 0; i4 < 4; ++i4) s += f[i4] * w1[i4 * 8 + o];
        h1[o] = fmaxf(s, 0.0f);
    }
    float h2[8];
    #pragma unroll
    for (int o = 0; o < 8; ++o) {
        float s = b2[o];
        #pragma unroll
        for (int i8 = 0; i8 < 8; ++i8) s += h1[i8] * w2[i8 * 8 + o];
        h2[o] = fmaxf(s, 0.0f);
    }
    float mv = b3s;
    #pragma unroll
    for (int i8 = 0; i8 < 8; ++i8) mv += h2[i8] * w3[i8];
    mv = fminf(fmaxf(mv, -10.0f), 10.0f);

    mbuf[(size_t)bi * S + j] = mv;
}

// ---------------------------------------------------------------------------
// K3: FULLY FUSED per-(b,h,32-row-chunk):
//   scores (QK^T/8 with +-2 halo) -> Toeplitz conv -> +bias +m
//   -> in-place softmax -> PV -> attn (B,S,H,DH)
// Conv identity:
//   out[i,j] = sum_r sum_t scores[i+r-2, t] * kcomb[r][t-j+127]
//   kcomb[r] = (c5[r] + (1<=r<=3)*c3[r-1] + (r==2)*c1[0]) / 3
// LDS: srows 36KB + pool 19KB = 56KB.  pool = kcp(2560f)+qrows(2304f),
// later reused as vtile(4096f) for PV.
// ---------------------------------------------------------------------------
__global__ __launch_bounds__(256) void fused_scores_conv_sm_pv_kernel(
    const float* __restrict__ q, const float* __restrict__ kbuf,
    const float* __restrict__ vbuf,
    const float* __restrict__ c1k, const float* __restrict__ c1b,
    const float* __restrict__ c3k, const float* __restrict__ c3b,
    const float* __restrict__ c5k, const float* __restrict__ c5b,
    const float* __restrict__ mbuf,
    float* __restrict__ attn)
{
    __shared__ __align__(16) float srows[36][256];   // score rows i0-2 .. i0+33
    __shared__ __align__(16) float pool[4864];       // kcp | qrows, later vtile
    #define KCP(r,x)    pool[(r)*512 + (x)]
    #define QROWS(r,d)  pool[2560 + (r)*64 + (d)]
    #define VTILE(i)    pool[i]

    const int tid = threadIdx.x;
    const int n = blockIdx.y;          // b*H + h
    const int bb = n >> 3, hh = n & 7;
    const int i0 = blockIdx.x * 32;

    // stage padded combined conv kernels: KCP[r][x] = kcomb[r][x-128], else 0
    for (int idx = tid; idx < 5 * 512; idx += 256) {
        const int r = idx >> 9, xx = idx & 511;
        const int ki = xx - 128;
        float val = 0.0f;
        if (ki >= 0 && ki < 256) {
            val = c5k[r * 256 + ki];
            if (r >= 1 && r <= 3) val += c3k[(r - 1) * 256 + ki];
            if (r == 2)           val += c1k[ki];
            val *= (1.0f / 3.0f);
        }
        KCP(r, xx) = val;
    }
    // stage q rows (with halo, zero out-of-range)
    for (int idx = tid; idx < 36 * 64; idx += 256) {
        const int rr = idx >> 6, dd = idx & 63;
        const int i = i0 + rr - 2;
        QROWS(rr, dd) = (i >= 0 && i < S) ? q[((size_t)n * S + i) * DH + dd] : 0.0f;
    }
    __syncthreads();

    // ---- phase 1: scores for 36 rows; thread = column t ----
    {
        const int t = tid;
        float acc[36];
        #pragma unroll
        for (int rr = 0; rr < 36; ++rr) acc[rr] = 0.0f;
        const float* krow = kbuf + ((size_t)n * S + t) * DH;
        for (int d0 = 0; d0 < DH; d0 += 16) {
            float kreg[16];
            #pragma unroll
            for (int u = 0; u < 4; ++u)
                *(float4*)&kreg[u * 4] = *(const float4*)(krow + d0 + u * 4);
            #pragma unroll
            for (int rr = 0; rr < 36; ++rr) {
                float qreg[16];
                #pragma unroll
                for (int u = 0; u < 4; ++u)
                    *(float4*)&qreg[u * 4] = *(const float4*)&QROWS(rr, d0 + u * 4);
                float s = 0.0f;
                #pragma unroll
                for (int u = 0; u < 16; ++u) s += qreg[u] * kreg[u];
                acc[rr] += s;
            }
        }
        #pragma unroll
        for (int rr = 0; rr < 36; ++rr) srows[rr][t] = acc[rr] * 0.125f;
    }
    __syncthreads();

    // ---- phase 2: Toeplitz conv.  thread (tr,tc): rows tr*4+{0..3}, cols tc+32*{0..7}
    const int tc = tid & 31, tr = tid >> 5;
    float acc2[4][8] = {};
    for (int r = 0; r < 5; ++r) {
        for (int t4 = 0; t4 < 256; t4 += 4) {
            float4 sv[4];
            #pragma unroll
            for (int ri = 0; ri < 4; ++ri)
                sv[ri] = *(const float4*)&srows[tr * 4 + ri + r][t4];
            #pragma unroll
            for (int jj = 0; jj < 8; ++jj) {
                const int xb = t4 - (tc + 32 * jj) + 255;   // in [0,507]
                const float kc0 = KCP(r, xb + 0);
                const float kc1 = KCP(r, xb + 1);
                const float kc2 = KCP(r, xb + 2);
                const float kc3 = KCP(r, xb + 3);
                #pragma unroll
                for (int ri = 0; ri < 4; ++ri)
                    acc2[ri][jj] += sv[ri].x * kc0 + sv[ri].y * kc1
                                  + sv[ri].z * kc2 + sv[ri].w * kc3;
            }
        }
    }
    __syncthreads();   // all conv reads of srows complete

    // ---- phase 2.5: + bias + m, write back in place (rows 0..31) ----
    const float bias_comb = (c1b[0] + c3b[0] + c5b[0]) * (1.0f / 3.0f);
    #pragma unroll
    for (int ri = 0; ri < 4; ++ri) {
        const int i = i0 + tr * 4 + ri;
        #pragma unroll
        for (int jj = 0; jj < 8; ++jj) {
            const int j = tc + 32 * jj;
            srows[tr * 4 + ri][j] = acc2[ri][jj] + bias_comb
                                  + mbuf[((size_t)bb * S + i) * S + j];
        }
    }
    __syncthreads();

    // ---- phase 3: in-place softmax; wave w handles rows w*8 .. w*8+7 ----
    {
        const int lane = tid & 63, wv = tid >> 6;
        for (int rr8 = 0; rr8 < 8; ++rr8) {
            const int row = wv * 8 + rr8;
            float sv[4];
            #pragma unroll
            for (int u = 0; u < 4; ++u) sv[u] = srows[row][lane + 64 * u];
            float mx = fmaxf(fmaxf(sv[0], sv[1]), fmaxf(sv[2], sv[3]));
            #pragma unroll
            for (int msk = 32; msk >= 1; msk >>= 1) mx = fmaxf(mx, __shfl_xor(mx, msk));
            float ev[4], sm = 0.0f;
            #pragma unroll
            for (int u = 0; u < 4; ++u) { ev[u] = expf(sv[u] - mx); sm += ev[u]; }
            #pragma unroll
            for (int msk = 32; msk >= 1; msk >>= 1) sm += __shfl_xor(sm, msk);
            const float inv = 1.0f / sm;
            #pragma unroll
            for (int u = 0; u < 4; ++u) srows[row][lane + 64 * u] = ev[u] * inv;
        }
    }

    // ---- phase 4: PV with V staged in 64x64 LDS chunks (aliases pool) ----
    const int pr = tid >> 4;            // 0..15 (weight rows pr, pr+16)
    const int pc = (tid & 15) * 4;      // dd base
    float pacc[2][4] = {};
    for (int t0 = 0; t0 < 256; t0 += 64) {
        __syncthreads();   // prior vtile reads (or softmax/kcp use) complete
        #pragma unroll
        for (int it = 0; it < 4; ++it) {
            const int id = tid + 256 * it;       // float4 id 0..1023
            const int tt = id >> 4, c4 = (id & 15) * 4;
            *(float4*)&VTILE(tt * 64 + c4) =
                *(const float4*)&vbuf[((size_t)n * S + t0 + tt) * DH + c4];
        }
        __syncthreads();
        #pragma unroll
        for (int half = 0; half < 2; ++half) {
            const int row = pr + 16 * half;
            #pragma unroll 4
            for (int tt = 0; tt < 64; ++tt) {
                const float wv = srows[row][t0 + tt];
                const float4 v4 = *(const float4*)&VTILE(tt * 64 + pc);
                pacc[half][0] += wv * v4.x;
                pacc[half][1] += wv * v4.y;
                pacc[half][2] += wv * v4.z;
                pacc[half][3] += wv * v4.w;
            }
        }
    }
    #pragma unroll
    for (int half = 0; half < 2; ++half) {
        const int i = i0 + pr + 16 * half;
        float4 o4 = make_float4(pacc[half][0], pacc[half][1], pacc[half][2], pacc[half][3]);
        *(float4*)&attn[(((size_t)bb * S + i) * H + hh) * DH + pc] = o4;
    }
    #undef KCP
    #undef QROWS
    #undef VTILE
}

// ---------------------------------------------------------------------------
// K5: output dense GEMM: attn(16384x512) @ dense_w(512x512) + dense_b
// ---------------------------------------------------------------------------
__global__ __launch_bounds__(256) void gemm_dense_kernel(
    const float* __restrict__ a, const float* __restrict__ w,
    const float* __restrict__ bias, float* __restrict__ out)
{
    const int row0 = blockIdx.y * 64;
    const int col0 = blockIdx.x * 64;

    __shared__ float As[16][68];
    __shared__ float Bs[16][64];

    const int tid = threadIdx.x;
    const int tx = tid & 15, ty = tid >> 4;

    float acc[4][4] = {};

    for (int k0 = 0; k0 < DD; k0 += 16) {
        {
            const int kk = tid & 15;
            const int rb = tid >> 4;
            #pragma unroll
            for (int it = 0; it < 4; ++it) {
                const int rr = rb + 16 * it;
                As[kk][rr] = a[(size_t)(row0 + rr) * DD + k0 + kk];
            }
            const int cc = tid & 63;
            const int kb = tid >> 6;
            #pragma unroll
            for (int it = 0; it < 4; ++it) {
                const int kk2 = kb + 4 * it;
                Bs[kk2][cc] = w[(size_t)(k0 + kk2) * DD + col0 + cc];
            }
        }
        __syncthreads();
        #pragma unroll
        for (int kk = 0; kk < 16; ++kk) {
            const float4 a4 = *(const float4*)&As[kk][ty * 4];
            const float4 b4 = *(const float4*)&Bs[kk][tx * 4];
            const float av[4] = {a4.x, a4.y, a4.z, a4.w};
            const float bv[4] = {b4.x, b4.y, b4.z, b4.w};
            #pragma unroll
            for (int i2 = 0; i2 < 4; ++i2)
                #pragma unroll
                for (int j2 = 0; j2 < 4; ++j2)
                    acc[i2][j2] += av[i2] * bv[j2];
        }
        __syncthreads();
    }

    #pragma unroll
    for (int i2 = 0; i2 < 4; ++i2) {
        const int row = row0 + ty * 4 + i2;
        #pragma unroll
        for (int j2 = 0; j2 < 4; ++j2) {
            const int c = col0 + tx * 4 + j2;
            out[(size_t)row * DD + c] = acc[i2][j2] + bias[c];
        }
    }
}

// ---------------------------------------------------------------------------
// launcher
// ---------------------------------------------------------------------------
extern "C" void kernel_launch(void* const* d_in, const int* in_sizes, int n_in,
                              void* d_out, int out_size, void* d_ws, size_t ws_size,
                              hipStream_t stream)
{
    (void)in_sizes; (void)n_in; (void)out_size; (void)ws_size;

    const float* x        = (const float*)d_in[0];
    const float* particles= (const float*)d_in[1];
    const float* wq       = (const float*)d_in[2];
    const float* wk       = (const float*)d_in[3];
    const float* wv       = (const float*)d_in[4];
    const float* dense_w  = (const float*)d_in[5];
    const float* dense_b  = (const float*)d_in[6];
    const float* c1k      = (const float*)d_in[7];
    const float* c1b      = (const float*)d_in[8];
    const float* c3k      = (const float*)d_in[9];
    const float* c3b      = (const float*)d_in[10];
    const float* c5k      = (const float*)d_in[11];
    const float* c5b      = (const float*)d_in[12];
    const float* mw1      = (const float*)d_in[13];
    const float* mb1      = (const float*)d_in[14];
    const float* mw2      = (const float*)d_in[15];
    const float* mb2      = (const float*)d_in[16];
    const float* mw3      = (const float*)d_in[17];
    const float* mb3      = (const float*)d_in[18];
    float* out = (float*)d_out;

    // workspace layout (floats); total = 37,748,736 floats = 144 MB
    float* ws   = (float*)d_ws;
    float* qb   = ws;                                  // BH*S*DH = 8M floats
    float* kb   = qb  + (size_t)BH * S * DH;           // 8M
    float* vb   = kb  + (size_t)BH * S * DH;           // 8M
    float* mb   = vb  + (size_t)BH * S * DH;           // B*S*S = 4M
    float* attn = mb  + (size_t)B  * S * S;            // B*S*D = 8M

    gemm_qkv_kernel<<<dim3(8, 256, 3), 256, 0, stream>>>(x, wq, wk, wv, qb, kb, vb);
    pairwise_mlp_kernel<<<dim3(B * S), 256, 0, stream>>>(particles, mw1, mb1, mw2, mb2, mw3, mb3, mb);
    fused_scores_conv_sm_pv_kernel<<<dim3(8, BH), 256, 0, stream>>>(
        qb, kb, vb, c1k, c1b, c3k, c3b, c5k, c5b, mb, attn);
    gemm_dense_kernel<<<dim3(8, 256), 256, 0, stream>>>(attn, dense_w, dense_b, out);
}

// Round 3
// 739.507 us; speedup vs baseline: 2.6738x; 2.6738x over previous
//
#include <hip/hip_runtime.h>
#include <hip/hip_bf16.h>
#include <math.h>

// Problem constants
#define B   64
#define S   256
#define DD  512
#define H   8
#define DH  64
#define BH  (B*H)   // 512

typedef short s16x8 __attribute__((ext_vector_type(8)));
typedef short s16x4 __attribute__((ext_vector_type(4)));
typedef float f32x4 __attribute__((ext_vector_type(4)));

__device__ __forceinline__ short f2bf(float f) {
    union { float f; unsigned u; } v; v.f = f;
    unsigned u = v.u;
    u += 0x7FFFu + ((u >> 16) & 1u);   // RNE
    return (short)(u >> 16);
}

// ---------------------------------------------------------------------------
// K1: QKV projections (unchanged, known-good).
// ---------------------------------------------------------------------------
__global__ __launch_bounds__(256) void gemm_qkv_kernel(
    const float* __restrict__ x,
    const float* __restrict__ wq, const float* __restrict__ wk, const float* __restrict__ wv,
    float* __restrict__ qo, float* __restrict__ ko, float* __restrict__ vo)
{
    const int zid = blockIdx.z;
    const float* w = (zid == 0) ? wq : (zid == 1) ? wk : wv;
    float* dst     = (zid == 0) ? qo : (zid == 1) ? ko : vo;

    const int row0 = blockIdx.y * 64;
    const int col0 = blockIdx.x * 64;

    __shared__ float As[16][68];
    __shared__ float Bs[16][64];

    const int tid = threadIdx.x;
    const int tx = tid & 15, ty = tid >> 4;

    float acc[4][4] = {};

    for (int k0 = 0; k0 < DD; k0 += 16) {
        {
            const int kk = tid & 15;
            const int rb = tid >> 4;
            #pragma unroll
            for (int it = 0; it < 4; ++it) {
                const int rr = rb + 16 * it;
                As[kk][rr] = x[(size_t)(row0 + rr) * DD + k0 + kk];
            }
            const int cc = tid & 63;
            const int kb = tid >> 6;
            #pragma unroll
            for (int it = 0; it < 4; ++it) {
                const int kk2 = kb + 4 * it;
                Bs[kk2][cc] = w[(size_t)(k0 + kk2) * DD + col0 + cc];
            }
        }
        __syncthreads();
        #pragma unroll
        for (int kk = 0; kk < 16; ++kk) {
            const float4 a4 = *(const float4*)&As[kk][ty * 4];
            const float4 b4 = *(const float4*)&Bs[kk][tx * 4];
            const float av[4] = {a4.x, a4.y, a4.z, a4.w};
            const float bv[4] = {b4.x, b4.y, b4.z, b4.w};
            #pragma unroll
            for (int i2 = 0; i2 < 4; ++i2)
                #pragma unroll
                for (int j2 = 0; j2 < 4; ++j2)
                    acc[i2][j2] += av[i2] * bv[j2];
        }
        __syncthreads();
    }

    #pragma unroll
    for (int i2 = 0; i2 < 4; ++i2) {
        const int row = row0 + ty * 4 + i2;
        const int bb = row >> 8, ss = row & 255;
        #pragma unroll
        for (int j2 = 0; j2 < 4; ++j2) {
            const int c = col0 + tx * 4 + j2;
            const int hh = c >> 6, dd = c & 63;
            dst[(((size_t)(bb * H + hh)) * S + ss) * DH + dd] = acc[i2][j2];
        }
    }
}

// ---------------------------------------------------------------------------
// K2: pairwise features + tiny MLP -> m[b][i][j]  (unchanged, known-good)
// ---------------------------------------------------------------------------
__global__ __launch_bounds__(256) void pairwise_mlp_kernel(
    const float* __restrict__ particles,
    const float* __restrict__ mw1, const float* __restrict__ mb1,
    const float* __restrict__ mw2, const float* __restrict__ mb2,
    const float* __restrict__ mw3, const float* __restrict__ mb3,
    float* __restrict__ mbuf)
{
    __shared__ float w1[32], b1[8], w2[64], b2[8], w3[8];
    __shared__ float b3s;
    const int tid = threadIdx.x;
    if (tid < 32)                 w1[tid]        = mw1[tid];
    if (tid >= 32 && tid < 40)    b1[tid - 32]   = mb1[tid - 32];
    if (tid >= 64 && tid < 128)   w2[tid - 64]   = mw2[tid - 64];
    if (tid >= 128 && tid < 136)  b2[tid - 128]  = mb2[tid - 128];
    if (tid >= 136 && tid < 144)  w3[tid - 136]  = mw3[tid - 136];
    if (tid == 144)               b3s            = mb3[0];

    const int bi = blockIdx.x;
    const int bb = bi >> 8;
    const float pt_i  = particles[(size_t)bi * 3 + 0];
    const float eta_i = particles[(size_t)bi * 3 + 1];
    const float phi_i = particles[(size_t)bi * 3 + 2];

    const int j = tid;
    const float* pj = particles + ((size_t)(bb * S) + j) * 3;
    const float pt_j = pj[0], eta_j = pj[1], phi_j = pj[2];

    __syncthreads();

    const float d_eta = eta_i - eta_j;
    const float dp    = phi_i - phi_j;
    const float d_phi = atan2f(sinf(dp), cosf(dp));
    const float delta = sqrtf(d_eta * d_eta + d_phi * d_phi);
    const float min_pt = fminf(pt_i, pt_j);
    const float kT = min_pt * delta;
    const float zf = min_pt / (pt_i + pt_j + 1e-8f);
    const float cd = cosf(d_phi);
    const float m2 = fmaxf(pt_i * pt_i + pt_j * pt_j - 2.0f * pt_i * pt_j * cd, 1e-8f);

    const float eps = 1e-8f;
    const float f[4] = { logf(fmaxf(delta, eps)),
                         logf(fmaxf(kT,    eps)),
                         logf(fmaxf(zf,    eps)),
                         logf(m2) };

    float h1[8];
    #pragma unroll
    for (int o = 0; o < 8; ++o) {
        float s = b1[o];
        #pragma unroll
        for (int i4 = 0; i4 < 4; ++i4) s += f[i4] * w1[i4 * 8 + o];
        h1[o] = fmaxf(s, 0.0f);
    }
    float h2[8];
    #pragma unroll
    for (int o = 0; o < 8; ++o) {
        float s = b2[o];
        #pragma unroll
        for (int i8 = 0; i8 < 8; ++i8) s += h1[i8] * w2[i8 * 8 + o];
        h2[o] = fmaxf(s, 0.0f);
    }
    float mv = b3s;
    #pragma unroll
    for (int i8 = 0; i8 < 8; ++i8) mv += h2[i8] * w3[i8];
    mv = fminf(fmaxf(mv, -10.0f), 10.0f);

    mbuf[(size_t)bi * S + j] = mv;
}

// ---------------------------------------------------------------------------
// K3: MFMA-fused  scores -> Toeplitz conv -> +bias+m -> softmax -> PV
// Block = (64-row chunk, head). 256 threads = 4 waves.
//
// MFMA 16x16x32 bf16 fragment scheme:
//   A: row = lane&15,  k = 8*(lane>>4)+e   (8 bf16 = b128)
//   B: col = lane&15,  k = 8*(lane>>4)+e
//   C/D: col = lane&15, row = (lane>>4)*4 + reg    [m89-verified]
//
// Conv identity: out[i,j] = sum_r sum_t scores[i+r-2,t] * kcomb[r][t-j+127]
//   kcomb[r] = (c5[r] + (1<=r<=3)*c3[r-1] + (r==2)*c1[0]) / 3
// B-frags come from kcp4: 4 phase-shifted copies of zero-padded kcomb so that
// any 4-consecutive-element window is an aligned ds_read_b64.
//
// LDS pool (64KB, 2 blocks/CU):
//   phase 1-2: SC scores bf16 [80][256] swizzled (40960) | kcp4 (20608) | RED (1KB)
//   phase 3-4: PB P bf16 [64][256] (32768) | VT V^T bf16 [64][256] (32768)
// ---------------------------------------------------------------------------
__global__ __launch_bounds__(256) void fused_mfma_kernel(
    const float* __restrict__ q, const float* __restrict__ kbuf,
    const float* __restrict__ vbuf,
    const float* __restrict__ c1k, const float* __restrict__ c1b,
    const float* __restrict__ c3k, const float* __restrict__ c3b,
    const float* __restrict__ c5k, const float* __restrict__ c5b,
    const float* __restrict__ mbuf,
    float* __restrict__ attn)
{
    __shared__ __align__(16) char pool[65536];
    char* SC  = pool;                       // scores bf16 [80][512B], swizzled
    char* KC  = pool + 40960;               // kcp4: 4 copies x 5152B
    float* RED = (float*)(pool + 61568);    // [64][4] cross-wave reduce
    char* PB  = pool;                       // P bf16 [64][512B] (aliases SC)
    char* VT  = pool + 32768;               // V^T bf16 [64][512B] (aliases KC+)

    const int tid  = threadIdx.x;
    const int lane = tid & 63;
    const int w    = tid >> 6;
    const int l15  = lane & 15, l4 = lane >> 4;
    const int head = blockIdx.y;            // b*H + h
    const int bb   = head >> 3, hh = head & 7;
    const int i0   = blockIdx.x * 64;
    const int cb   = w * 64;                // this wave's column base

    // ---- stage kcp4: copy p holds kcp[x] = padded_kcomb(x+p) ----
    for (int p = 0; p < 4; ++p)
        for (int e = tid; e < 2560; e += 256) {
            const int r = e >> 9, x = e & 511;
            const int y = x + p;
            float val = 0.f;
            if (y >= 128 && y < 384) {
                const int ki = y - 128;
                val = c5k[r * 256 + ki];
                if (r >= 1 && r <= 3) val += c3k[(r - 1) * 256 + ki];
                if (r == 2)           val += c1k[ki];
                val *= (1.f / 3.f);
            }
            *(short*)(KC + p * 5152 + r * 1024 + x * 2) = f2bf(val);
        }

    // ---- phase 1: scores rows i0-8 .. i0+71 (80 rows), /8 folded into Q ----
    {
        const float* kb_h = kbuf + (size_t)head * S * DH;
        const float* qb_h = q    + (size_t)head * S * DH;
        f32x4 sacc[5][4];
        #pragma unroll
        for (int rt = 0; rt < 5; ++rt)
            #pragma unroll
            for (int n = 0; n < 4; ++n)
                sacc[rt][n] = (f32x4){0.f, 0.f, 0.f, 0.f};

        #pragma unroll
        for (int kk = 0; kk < 2; ++kk) {
            s16x8 bfr[4];
            #pragma unroll
            for (int n = 0; n < 4; ++n) {
                const int t = cb + n * 16 + l15;
                const float* src = kb_h + t * 64 + kk * 32 + 8 * l4;
                const float4 fa = *(const float4*)src;
                const float4 fb = *(const float4*)(src + 4);
                bfr[n] = (s16x8){ f2bf(fa.x), f2bf(fa.y), f2bf(fa.z), f2bf(fa.w),
                                  f2bf(fb.x), f2bf(fb.y), f2bf(fb.z), f2bf(fb.w) };
            }
            #pragma unroll
            for (int rt = 0; rt < 5; ++rt) {
                const int qrow = i0 - 8 + rt * 16 + l15;
                s16x8 afr = (s16x8){0,0,0,0,0,0,0,0};
                if (qrow >= 0 && qrow < S) {
                    const float* src = qb_h + qrow * 64 + kk * 32 + 8 * l4;
                    const float4 fa = *(const float4*)src;
                    const float4 fb = *(const float4*)(src + 4);
                    afr = (s16x8){ f2bf(fa.x * 0.125f), f2bf(fa.y * 0.125f),
                                   f2bf(fa.z * 0.125f), f2bf(fa.w * 0.125f),
                                   f2bf(fb.x * 0.125f), f2bf(fb.y * 0.125f),
                                   f2bf(fb.z * 0.125f), f2bf(fb.w * 0.125f) };
                }
                #pragma unroll
                for (int n = 0; n < 4; ++n)
                    sacc[rt][n] = __builtin_amdgcn_mfma_f32_16x16x32_bf16(
                                      afr, bfr[n], sacc[rt][n], 0, 0, 0);
            }
        }
        // C-layout -> bf16 swizzled LDS
        #pragma unroll
        for (int rt = 0; rt < 5; ++rt)
            #pragma unroll
            for (int n = 0; n < 4; ++n)
                #pragma unroll
                for (int rg = 0; rg < 4; ++rg) {
                    const int srow = rt * 16 + l4 * 4 + rg;
                    const int col  = cb + n * 16 + l15;
                    const int byt  = (srow * 512 + col * 2) ^ ((srow & 7) << 4);
                    *(short*)(SC + byt) = f2bf(sacc[rt][n][rg]);
                }
    }
    __syncthreads();

    // ---- phase 2: Toeplitz conv via MFMA; out 64x256, wave = 64-col strip ----
    f32x4 cacc[4][4];
    #pragma unroll
    for (int rt = 0; rt < 4; ++rt)
        #pragma unroll
        for (int n = 0; n < 4; ++n)
            cacc[rt][n] = (f32x4){0.f, 0.f, 0.f, 0.f};

    {
        const int p_l = (255 - l15) & 3;            // x0 mod 4 is lane-invariant
        const char* kcb = KC + p_l * 5152;
        const int xl = 255 + 8 * l4 - l15 - cb - p_l;  // (x0 - p) base
        #pragma unroll
        for (int r = 0; r < 5; ++r) {
            #pragma unroll
            for (int kk = 0; kk < 8; ++kk) {
                s16x8 bfr[4];
                #pragma unroll
                for (int n = 0; n < 4; ++n) {
                    const int off = (xl + kk * 32 - 16 * n) * 2 + r * 1024;
                    union { s16x8 v; struct { s16x4 lo; s16x4 hi; } h; } u;
                    u.h.lo = *(const s16x4*)(kcb + off);
                    u.h.hi = *(const s16x4*)(kcb + off + 8);
                    bfr[n] = u.v;
                }
                #pragma unroll
                for (int rt = 0; rt < 4; ++rt) {
                    const int sr  = rt * 16 + l15 + r + 6;   // score-buffer row
                    const int byt = (sr * 512 + kk * 64 + 16 * l4) ^ ((sr & 7) << 4);
                    const s16x8 afr = *(const s16x8*)(SC + byt);
                    #pragma unroll
                    for (int n = 0; n < 4; ++n)
                        cacc[rt][n] = __builtin_amdgcn_mfma_f32_16x16x32_bf16(
                                          afr, bfr[n], cacc[rt][n], 0, 0, 0);
                }
            }
        }
    }

    // ---- phase 2.5: + combined bias + m ----
    {
        const float bias_comb = (c1b[0] + c3b[0] + c5b[0]) * (1.f / 3.f);
        const float* mrow = mbuf + (size_t)bb * 65536;
        #pragma unroll
        for (int rt = 0; rt < 4; ++rt)
            #pragma unroll
            for (int rg = 0; rg < 4; ++rg) {
                const int i = i0 + rt * 16 + l4 * 4 + rg;
                #pragma unroll
                for (int n = 0; n < 4; ++n) {
                    const int j = cb + n * 16 + l15;
                    cacc[rt][n][rg] += bias_comb + mrow[i * 256 + j];
                }
            }
    }

    // ---- phase 3: softmax (in-register + 1KB cross-wave combine) ----
    float rmax[4][4];
    #pragma unroll
    for (int rt = 0; rt < 4; ++rt)
        #pragma unroll
        for (int rg = 0; rg < 4; ++rg) {
            float mx = fmaxf(fmaxf(cacc[rt][0][rg], cacc[rt][1][rg]),
                             fmaxf(cacc[rt][2][rg], cacc[rt][3][rg]));
            mx = fmaxf(mx, __shfl_xor(mx, 1));
            mx = fmaxf(mx, __shfl_xor(mx, 2));
            mx = fmaxf(mx, __shfl_xor(mx, 4));
            mx = fmaxf(mx, __shfl_xor(mx, 8));
            rmax[rt][rg] = mx;
        }
    if (l15 == 0) {
        #pragma unroll
        for (int rt = 0; rt < 4; ++rt)
            #pragma unroll
            for (int rg = 0; rg < 4; ++rg)
                RED[(rt * 16 + l4 * 4 + rg) * 4 + w] = rmax[rt][rg];
    }
    __syncthreads();
    #pragma unroll
    for (int rt = 0; rt < 4; ++rt)
        #pragma unroll
        for (int rg = 0; rg < 4; ++rg) {
            const int row = rt * 16 + l4 * 4 + rg;
            rmax[rt][rg] = fmaxf(fmaxf(RED[row * 4 + 0], RED[row * 4 + 1]),
                                 fmaxf(RED[row * 4 + 2], RED[row * 4 + 3]));
        }
    __syncthreads();   // RED reusable

    float rinv[4][4];
    #pragma unroll
    for (int rt = 0; rt < 4; ++rt)
        #pragma unroll
        for (int rg = 0; rg < 4; ++rg) {
            float sm = 0.f;
            #pragma unroll
            for (int n = 0; n < 4; ++n) {
                const float e = __expf(cacc[rt][n][rg] - rmax[rt][rg]);
                cacc[rt][n][rg] = e;
                sm += e;
            }
            sm += __shfl_xor(sm, 1);
            sm += __shfl_xor(sm, 2);
            sm += __shfl_xor(sm, 4);
            sm += __shfl_xor(sm, 8);
            rinv[rt][rg] = sm;   // partial (this wave's 64 cols)
        }
    if (l15 == 0) {
        #pragma unroll
        for (int rt = 0; rt < 4; ++rt)
            #pragma unroll
            for (int rg = 0; rg < 4; ++rg)
                RED[(rt * 16 + l4 * 4 + rg) * 4 + w] = rinv[rt][rg];
    }
    __syncthreads();
    #pragma unroll
    for (int rt = 0; rt < 4; ++rt)
        #pragma unroll
        for (int rg = 0; rg < 4; ++rg) {
            const int row = rt * 16 + l4 * 4 + rg;
            const float tot = (RED[row * 4 + 0] + RED[row * 4 + 1])
                            + (RED[row * 4 + 2] + RED[row * 4 + 3]);
            rinv[rt][rg] = 1.f / tot;
        }
    __syncthreads();   // all RED reads done before VT overwrites it

    // ---- write P (bf16, swizzled) + build V^T (bf16, swizzled) ----
    #pragma unroll
    for (int rt = 0; rt < 4; ++rt)
        #pragma unroll
        for (int n = 0; n < 4; ++n)
            #pragma unroll
            for (int rg = 0; rg < 4; ++rg) {
                const int row = rt * 16 + l4 * 4 + rg;
                const int col = cb + n * 16 + l15;
                const int byt = (row * 512 + col * 2) ^ ((row & 7) << 4);
                *(short*)(PB + byt) = f2bf(cacc[rt][n][rg] * rinv[rt][rg]);
            }
    {
        const float* vb_h = vbuf + (size_t)head * S * DH;
        for (int it = 0; it < 16; ++it) {
            const int idx = tid + it * 256;
            const int t = idx >> 4, d0 = (idx & 15) * 4;
            const float4 v4 = *(const float4*)(vb_h + t * 64 + d0);
            const float vv[4] = {v4.x, v4.y, v4.z, v4.w};
            #pragma unroll
            for (int c = 0; c < 4; ++c) {
                const int d = d0 + c;
                const int byt = (d * 512 + t * 2) ^ ((d & 7) << 4);
                *(short*)(VT + byt) = f2bf(vv[c]);
            }
        }
    }
    __syncthreads();

    // ---- phase 4: PV via MFMA; wave w handles rows w*16..w*16+15 ----
    f32x4 pacc[4];
    #pragma unroll
    for (int n = 0; n < 4; ++n) pacc[n] = (f32x4){0.f, 0.f, 0.f, 0.f};
    #pragma unroll
    for (int kk = 0; kk < 8; ++kk) {
        const int prow = w * 16 + l15;
        const int byta = (prow * 512 + kk * 64 + 16 * l4) ^ ((prow & 7) << 4);
        const s16x8 pa = *(const s16x8*)(PB + byta);
        #pragma unroll
        for (int n = 0; n < 4; ++n) {
            const int d = n * 16 + l15;
            const int bytb = (d * 512 + kk * 64 + 16 * l4) ^ ((d & 7) << 4);
            const s16x8 vb8 = *(const s16x8*)(VT + bytb);
            pacc[n] = __builtin_amdgcn_mfma_f32_16x16x32_bf16(pa, vb8, pacc[n], 0, 0, 0);
        }
    }
    #pragma unroll
    for (int n = 0; n < 4; ++n)
        #pragma unroll
        for (int rg = 0; rg < 4; ++rg) {
            const int i = i0 + w * 16 + l4 * 4 + rg;
            const int d = n * 16 + l15;
            attn[(((size_t)bb * S + i) * H + hh) * DH + d] = pacc[n][rg];
        }
}

// ---------------------------------------------------------------------------
// K5: output dense GEMM (unchanged, known-good)
// ---------------------------------------------------------------------------
__global__ __launch_bounds__(256) void gemm_dense_kernel(
    const float* __restrict__ a, const float* __restrict__ w,
    const float* __restrict__ bias, float* __restrict__ out)
{
    const int row0 = blockIdx.y * 64;
    const int col0 = blockIdx.x * 64;

    __shared__ float As[16][68];
    __shared__ float Bs[16][64];

    const int tid = threadIdx.x;
    const int tx = tid & 15, ty = tid >> 4;

    float acc[4][4] = {};

    for (int k0 = 0; k0 < DD; k0 += 16) {
        {
            const int kk = tid & 15;
            const int rb = tid >> 4;
            #pragma unroll
            for (int it = 0; it < 4; ++it) {
                const int rr = rb + 16 * it;
                As[kk][rr] = a[(size_t)(row0 + rr) * DD + k0 + kk];
            }
            const int cc = tid & 63;
            const int kb = tid >> 6;
            #pragma unroll
            for (int it = 0; it < 4; ++it) {
                const int kk2 = kb + 4 * it;
                Bs[kk2][cc] = w[(size_t)(k0 + kk2) * DD + col0 + cc];
            }
        }
        __syncthreads();
        #pragma unroll
        for (int kk = 0; kk < 16; ++kk) {
            const float4 a4 = *(const float4*)&As[kk][ty * 4];
            const float4 b4 = *(const float4*)&Bs[kk][tx * 4];
            const float av[4] = {a4.x, a4.y, a4.z, a4.w};
            const float bv[4] = {b4.x, b4.y, b4.z, b4.w};
            #pragma unroll
            for (int i2 = 0; i2 < 4; ++i2)
                #pragma unroll
                for (int j2 = 0; j2 < 4; ++j2)
                    acc[i2][j2] += av[i2] * bv[j2];
        }
        __syncthreads();
    }

    #pragma unroll
    for (int i2 = 0; i2 < 4; ++i2) {
        const int row = row0 + ty * 4 + i2;
        #pragma unroll
        for (int j2 = 0; j2 < 4; ++j2) {
            const int c = col0 + tx * 4 + j2;
            out[(size_t)row * DD + c] = acc[i2][j2] + bias[c];
        }
    }
}

// ---------------------------------------------------------------------------
// launcher
// ---------------------------------------------------------------------------
extern "C" void kernel_launch(void* const* d_in, const int* in_sizes, int n_in,
                              void* d_out, int out_size, void* d_ws, size_t ws_size,
                              hipStream_t stream)
{
    (void)in_sizes; (void)n_in; (void)out_size; (void)ws_size;

    const float* x        = (const float*)d_in[0];
    const float* particles= (const float*)d_in[1];
    const float* wq       = (const float*)d_in[2];
    const float* wk       = (const float*)d_in[3];
    const float* wv       = (const float*)d_in[4];
    const float* dense_w  = (const float*)d_in[5];
    const float* dense_b  = (const float*)d_in[6];
    const float* c1k      = (const float*)d_in[7];
    const float* c1b      = (const float*)d_in[8];
    const float* c3k      = (const float*)d_in[9];
    const float* c3b      = (const float*)d_in[10];
    const float* c5k      = (const float*)d_in[11];
    const float* c5b      = (const float*)d_in[12];
    const float* mw1      = (const float*)d_in[13];
    const float* mb1      = (const float*)d_in[14];
    const float* mw2      = (const float*)d_in[15];
    const float* mb2      = (const float*)d_in[16];
    const float* mw3      = (const float*)d_in[17];
    const float* mb3      = (const float*)d_in[18];
    float* out = (float*)d_out;

    // workspace layout (floats); total = 37,748,736 floats = 144 MB
    float* ws   = (float*)d_ws;
    float* qb   = ws;                                  // BH*S*DH = 8M floats
    float* kb   = qb  + (size_t)BH * S * DH;           // 8M
    float* vb   = kb  + (size_t)BH * S * DH;           // 8M
    float* mb   = vb  + (size_t)BH * S * DH;           // B*S*S = 4M
    float* attn = mb  + (size_t)B  * S * S;            // B*S*D = 8M

    gemm_qkv_kernel<<<dim3(8, 256, 3), 256, 0, stream>>>(x, wq, wk, wv, qb, kb, vb);
    pairwise_mlp_kernel<<<dim3(B * S), 256, 0, stream>>>(particles, mw1, mb1, mw2, mb2, mw3, mb3, mb);
    fused_mfma_kernel<<<dim3(4, BH), 256, 0, stream>>>(
        qb, kb, vb, c1k, c1b, c3k, c3b, c5k, c5b, mb, attn);
    gemm_dense_kernel<<<dim3(8, 256), 256, 0, stream>>>(attn, dense_w, dense_b, out);
}

// Round 4
// 329.060 us; speedup vs baseline: 6.0089x; 2.2473x over previous
//
#include <hip/hip_runtime.h>
#include <hip/hip_bf16.h>
#include <math.h>

// Problem constants
#define B   64
#define S   256
#define DD  512
#define H   8
#define DH  64
#define BH  (B*H)   // 512

typedef short s16x8 __attribute__((ext_vector_type(8)));
typedef short s16x4 __attribute__((ext_vector_type(4)));
typedef float f32x4 __attribute__((ext_vector_type(4)));

typedef __attribute__((address_space(3))) unsigned int       lds_u32;
typedef __attribute__((address_space(1))) const unsigned int glb_u32;

__device__ __forceinline__ short f2bf(float f) {
    union { float f; unsigned u; } v; v.f = f;
    unsigned u = v.u;
    u += 0x7FFFu + ((u >> 16) & 1u);   // RNE
    return (short)(u >> 16);
}

__device__ __forceinline__ void glds16(const void* g, void* l) {
    __builtin_amdgcn_global_load_lds((glb_u32*)g, (lds_u32*)l, 16, 0, 0);
}

// ---------------------------------------------------------------------------
// P1: x (f32, 16384x512) -> xbf (bf16), vectorized 8 elems/thread
// ---------------------------------------------------------------------------
__global__ __launch_bounds__(256) void convert_x_kernel(
    const float* __restrict__ x, ushort* __restrict__ xbf)
{
    const int idx = blockIdx.x * 256 + threadIdx.x;
    const float4 f0 = *(const float4*)(x + (size_t)idx * 8);
    const float4 f1 = *(const float4*)(x + (size_t)idx * 8 + 4);
    s16x8 o = { f2bf(f0.x), f2bf(f0.y), f2bf(f0.z), f2bf(f0.w),
                f2bf(f1.x), f2bf(f1.y), f2bf(f1.z), f2bf(f1.w) };
    *(s16x8*)(xbf + (size_t)idx * 8) = o;
}

// ---------------------------------------------------------------------------
// P2: transpose+convert weights: wt[z][n][k] = w_z[k][n]  (bf16)
// z: 0=wq 1=wk 2=wv 3=dense_w.  32x32 LDS tile, 256 threads (32x8).
// ---------------------------------------------------------------------------
__global__ __launch_bounds__(256) void transpose_w_kernel(
    const float* __restrict__ wq, const float* __restrict__ wk,
    const float* __restrict__ wv, const float* __restrict__ wd,
    ushort* __restrict__ wt)
{
    __shared__ float tile[32][33];
    const int z = blockIdx.z;
    const float* w = (z == 0) ? wq : (z == 1) ? wk : (z == 2) ? wv : wd;
    const int k0 = blockIdx.y * 32, n0 = blockIdx.x * 32;
    const int tx = threadIdx.x & 31, ty = threadIdx.x >> 5;

    #pragma unroll
    for (int r = 0; r < 32; r += 8)
        tile[ty + r][tx] = w[(size_t)(k0 + ty + r) * DD + n0 + tx];
    __syncthreads();
    #pragma unroll
    for (int r = 0; r < 32; r += 8)
        wt[(size_t)z * DD * DD + (size_t)(n0 + ty + r) * DD + k0 + tx] =
            (ushort)f2bf(tile[tx][ty + r]);
}

// ---------------------------------------------------------------------------
// P3: bf16 MFMA GEMM, 128x128 tile, BK=64, 4 waves (2x2), m97 structure.
// A[M][512] bf16 row-major; Bt[N][512] bf16 (i.e. W^T, K-major rows).
// MODE 0: qkv -> scatter bf16 to (B,H,S,DH), z = blockIdx.z picks W & dst.
// MODE 1: dense -> f32 out[row][col] = acc + bias[col].
// ---------------------------------------------------------------------------
template<int MODE>
__global__ __launch_bounds__(256) void gemm_mfma_kernel(
    const ushort* __restrict__ A, const ushort* __restrict__ BtAll,
    ushort* __restrict__ qo, ushort* __restrict__ ko, ushort* __restrict__ vo,
    const float* __restrict__ bias, float* __restrict__ outf)
{
    __shared__ ushort As[128 * 64];
    __shared__ ushort Bs[128 * 64];

    const int tid  = threadIdx.x;
    const int lane = tid & 63, w = tid >> 6;
    const int l15  = lane & 15, l4 = lane >> 4;
    const int wr   = w >> 1, wc = w & 1;
    const int row0 = blockIdx.y * 128, col0 = blockIdx.x * 128;
    const ushort* Bt = BtAll + (MODE == 0 ? (size_t)blockIdx.z * DD * DD : 0);

    f32x4 acc[4][4];
    #pragma unroll
    for (int mt = 0; mt < 4; ++mt)
        #pragma unroll
        for (int nt = 0; nt < 4; ++nt)
            acc[mt][nt] = (f32x4){0.f, 0.f, 0.f, 0.f};

    const int arow = tid >> 3;          // + 32*i
    const int acol = (tid & 7) * 8;
    char* ldsA = (char*)As + (tid >> 6) * 1024;   // + 4096*i (+ lane*16 by HW)
    char* ldsB = (char*)Bs + (tid >> 6) * 1024;

    for (int k0 = 0; k0 < DD; k0 += 64) {
        #pragma unroll
        for (int i = 0; i < 4; ++i)
            glds16(A  + (size_t)(row0 + arow + 32 * i) * DD + k0 + acol,
                   ldsA + 4096 * i);
        #pragma unroll
        for (int i = 0; i < 4; ++i)
            glds16(Bt + (size_t)(col0 + arow + 32 * i) * DD + k0 + acol,
                   ldsB + 4096 * i);
        __syncthreads();

        #pragma unroll
        for (int kk = 0; kk < 2; ++kk) {
            s16x8 af[4], bf[4];
            #pragma unroll
            for (int mt = 0; mt < 4; ++mt) {
                const int row = wr * 64 + mt * 16 + l15;
                af[mt] = *(const s16x8*)((char*)As + row * 128 + kk * 64 + l4 * 16);
            }
            #pragma unroll
            for (int nt = 0; nt < 4; ++nt) {
                const int col = wc * 64 + nt * 16 + l15;
                bf[nt] = *(const s16x8*)((char*)Bs + col * 128 + kk * 64 + l4 * 16);
            }
            #pragma unroll
            for (int mt = 0; mt < 4; ++mt)
                #pragma unroll
                for (int nt = 0; nt < 4; ++nt)
                    acc[mt][nt] = __builtin_amdgcn_mfma_f32_16x16x32_bf16(
                                      af[mt], bf[nt], acc[mt][nt], 0, 0, 0);
        }
        __syncthreads();
    }

    if (MODE == 0) {
        ushort* dst = (blockIdx.z == 0) ? qo : (blockIdx.z == 1) ? ko : vo;
        #pragma unroll
        for (int mt = 0; mt < 4; ++mt)
            #pragma unroll
            for (int nt = 0; nt < 4; ++nt)
                #pragma unroll
                for (int rg = 0; rg < 4; ++rg) {
                    const int r = row0 + wr * 64 + mt * 16 + l4 * 4 + rg;
                    const int c = col0 + wc * 64 + nt * 16 + l15;
                    const int bb = r >> 8, ss = r & 255;
                    const int hh = c >> 6, dd = c & 63;
                    dst[(((size_t)(bb * H + hh)) * S + ss) * DH + dd] =
                        (ushort)f2bf(acc[mt][nt][rg]);
                }
    } else {
        #pragma unroll
        for (int mt = 0; mt < 4; ++mt)
            #pragma unroll
            for (int nt = 0; nt < 4; ++nt)
                #pragma unroll
                for (int rg = 0; rg < 4; ++rg) {
                    const int r = row0 + wr * 64 + mt * 16 + l4 * 4 + rg;
                    const int c = col0 + wc * 64 + nt * 16 + l15;
                    outf[(size_t)r * DD + c] = acc[mt][nt][rg] + bias[c];
                }
    }
}

// ---------------------------------------------------------------------------
// K2: pairwise features + tiny MLP -> m[b][i][j]  (unchanged, known-good)
// ---------------------------------------------------------------------------
__global__ __launch_bounds__(256) void pairwise_mlp_kernel(
    const float* __restrict__ particles,
    const float* __restrict__ mw1, const float* __restrict__ mb1,
    const float* __restrict__ mw2, const float* __restrict__ mb2,
    const float* __restrict__ mw3, const float* __restrict__ mb3,
    float* __restrict__ mbuf)
{
    __shared__ float w1[32], b1[8], w2[64], b2[8], w3[8];
    __shared__ float b3s;
    const int tid = threadIdx.x;
    if (tid < 32)                 w1[tid]        = mw1[tid];
    if (tid >= 32 && tid < 40)    b1[tid - 32]   = mb1[tid - 32];
    if (tid >= 64 && tid < 128)   w2[tid - 64]   = mw2[tid - 64];
    if (tid >= 128 && tid < 136)  b2[tid - 128]  = mb2[tid - 128];
    if (tid >= 136 && tid < 144)  w3[tid - 136]  = mw3[tid - 136];
    if (tid == 144)               b3s            = mb3[0];

    const int bi = blockIdx.x;
    const int bb = bi >> 8;
    const float pt_i  = particles[(size_t)bi * 3 + 0];
    const float eta_i = particles[(size_t)bi * 3 + 1];
    const float phi_i = particles[(size_t)bi * 3 + 2];

    const int j = tid;
    const float* pj = particles + ((size_t)(bb * S) + j) * 3;
    const float pt_j = pj[0], eta_j = pj[1], phi_j = pj[2];

    __syncthreads();

    const float d_eta = eta_i - eta_j;
    const float dp    = phi_i - phi_j;
    const float d_phi = atan2f(sinf(dp), cosf(dp));
    const float delta = sqrtf(d_eta * d_eta + d_phi * d_phi);
    const float min_pt = fminf(pt_i, pt_j);
    const float kT = min_pt * delta;
    const float zf = min_pt / (pt_i + pt_j + 1e-8f);
    const float cd = cosf(d_phi);
    const float m2 = fmaxf(pt_i * pt_i + pt_j * pt_j - 2.0f * pt_i * pt_j * cd, 1e-8f);

    const float eps = 1e-8f;
    const float f[4] = { logf(fmaxf(delta, eps)),
                         logf(fmaxf(kT,    eps)),
                         logf(fmaxf(zf,    eps)),
                         logf(m2) };

    float h1[8];
    #pragma unroll
    for (int o = 0; o < 8; ++o) {
        float s = b1[o];
        #pragma unroll
        for (int i4 = 0; i4 < 4; ++i4) s += f[i4] * w1[i4 * 8 + o];
        h1[o] = fmaxf(s, 0.0f);
    }
    float h2[8];
    #pragma unroll
    for (int o = 0; o < 8; ++o) {
        float s = b2[o];
        #pragma unroll
        for (int i8 = 0; i8 < 8; ++i8) s += h1[i8] * w2[i8 * 8 + o];
        h2[o] = fmaxf(s, 0.0f);
    }
    float mv = b3s;
    #pragma unroll
    for (int i8 = 0; i8 < 8; ++i8) mv += h2[i8] * w3[i8];
    mv = fminf(fmaxf(mv, -10.0f), 10.0f);

    mbuf[(size_t)bi * S + j] = mv;
}

// ---------------------------------------------------------------------------
// K3: MFMA-fused  scores -> Toeplitz conv -> +bias+m -> softmax -> PV
// q/k/v now bf16 in (B,H,S,DH); /8 folded into conv kernels (kcomb/24);
// attn written as bf16 [16384][512].
// ---------------------------------------------------------------------------
__global__ __launch_bounds__(256) void fused_mfma_kernel(
    const ushort* __restrict__ q, const ushort* __restrict__ kbuf,
    const ushort* __restrict__ vbuf,
    const float* __restrict__ c1k, const float* __restrict__ c1b,
    const float* __restrict__ c3k, const float* __restrict__ c3b,
    const float* __restrict__ c5k, const float* __restrict__ c5b,
    const float* __restrict__ mbuf,
    ushort* __restrict__ attn)
{
    __shared__ __align__(16) char pool[65536];
    char* SC  = pool;                       // scores bf16 [80][512B], swizzled
    char* KC  = pool + 40960;               // kcp4: 4 copies x 5152B
    float* RED = (float*)(pool + 61568);    // [64][4] cross-wave reduce
    char* PB  = pool;                       // P bf16 [64][512B] (aliases SC)
    char* VT  = pool + 32768;               // V^T bf16 [64][512B]

    const int tid  = threadIdx.x;
    const int lane = tid & 63;
    const int w    = tid >> 6;
    const int l15  = lane & 15, l4 = lane >> 4;
    const int head = blockIdx.y;            // b*H + h
    const int bb   = head >> 3, hh = head & 7;
    const int i0   = blockIdx.x * 64;
    const int cb   = w * 64;                // this wave's column base

    // ---- stage kcp4 (with /8 folded: kcomb/24) ----
    for (int p = 0; p < 4; ++p)
        for (int e = tid; e < 2560; e += 256) {
            const int r = e >> 9, x = e & 511;
            const int y = x + p;
            float val = 0.f;
            if (y >= 128 && y < 384) {
                const int ki = y - 128;
                val = c5k[r * 256 + ki];
                if (r >= 1 && r <= 3) val += c3k[(r - 1) * 256 + ki];
                if (r == 2)           val += c1k[ki];
                val *= (1.f / 24.f);
            }
            *(short*)(KC + p * 5152 + r * 1024 + x * 2) = f2bf(val);
        }

    // ---- phase 1: scores rows i0-8 .. i0+71 (80 rows), UNSCALED ----
    {
        const ushort* kb_h = kbuf + (size_t)head * S * DH;
        const ushort* qb_h = q    + (size_t)head * S * DH;
        f32x4 sacc[5][4];
        #pragma unroll
        for (int rt = 0; rt < 5; ++rt)
            #pragma unroll
            for (int n = 0; n < 4; ++n)
                sacc[rt][n] = (f32x4){0.f, 0.f, 0.f, 0.f};

        #pragma unroll
        for (int kk = 0; kk < 2; ++kk) {
            s16x8 bfr[4];
            #pragma unroll
            for (int n = 0; n < 4; ++n) {
                const int t = cb + n * 16 + l15;
                bfr[n] = *(const s16x8*)(kb_h + t * 64 + kk * 32 + 8 * l4);
            }
            #pragma unroll
            for (int rt = 0; rt < 5; ++rt) {
                const int qrow = i0 - 8 + rt * 16 + l15;
                s16x8 afr = (s16x8){0,0,0,0,0,0,0,0};
                if (qrow >= 0 && qrow < S)
                    afr = *(const s16x8*)(qb_h + qrow * 64 + kk * 32 + 8 * l4);
                #pragma unroll
                for (int n = 0; n < 4; ++n)
                    sacc[rt][n] = __builtin_amdgcn_mfma_f32_16x16x32_bf16(
                                      afr, bfr[n], sacc[rt][n], 0, 0, 0);
            }
        }
        #pragma unroll
        for (int rt = 0; rt < 5; ++rt)
            #pragma unroll
            for (int n = 0; n < 4; ++n)
                #pragma unroll
                for (int rg = 0; rg < 4; ++rg) {
                    const int srow = rt * 16 + l4 * 4 + rg;
                    const int col  = cb + n * 16 + l15;
                    const int byt  = (srow * 512 + col * 2) ^ ((srow & 7) << 4);
                    *(short*)(SC + byt) = f2bf(sacc[rt][n][rg]);
                }
    }
    __syncthreads();

    // ---- phase 2: Toeplitz conv via MFMA ----
    f32x4 cacc[4][4];
    #pragma unroll
    for (int rt = 0; rt < 4; ++rt)
        #pragma unroll
        for (int n = 0; n < 4; ++n)
            cacc[rt][n] = (f32x4){0.f, 0.f, 0.f, 0.f};

    {
        const int p_l = (255 - l15) & 3;
        const char* kcb = KC + p_l * 5152;
        const int xl = 255 + 8 * l4 - l15 - cb - p_l;
        #pragma unroll
        for (int r = 0; r < 5; ++r) {
            #pragma unroll
            for (int kk = 0; kk < 8; ++kk) {
                s16x8 bfr[4];
                #pragma unroll
                for (int n = 0; n < 4; ++n) {
                    const int off = (xl + kk * 32 - 16 * n) * 2 + r * 1024;
                    union { s16x8 v; struct { s16x4 lo; s16x4 hi; } h; } u;
                    u.h.lo = *(const s16x4*)(kcb + off);
                    u.h.hi = *(const s16x4*)(kcb + off + 8);
                    bfr[n] = u.v;
                }
                #pragma unroll
                for (int rt = 0; rt < 4; ++rt) {
                    const int sr  = rt * 16 + l15 + r + 6;
                    const int byt = (sr * 512 + kk * 64 + 16 * l4) ^ ((sr & 7) << 4);
                    const s16x8 afr = *(const s16x8*)(SC + byt);
                    #pragma unroll
                    for (int n = 0; n < 4; ++n)
                        cacc[rt][n] = __builtin_amdgcn_mfma_f32_16x16x32_bf16(
                                          afr, bfr[n], cacc[rt][n], 0, 0, 0);
                }
            }
        }
    }

    // ---- phase 2.5: + combined bias + m ----
    {
        const float bias_comb = (c1b[0] + c3b[0] + c5b[0]) * (1.f / 3.f);
        const float* mrow = mbuf + (size_t)bb * 65536;
        #pragma unroll
        for (int rt = 0; rt < 4; ++rt)
            #pragma unroll
            for (int rg = 0; rg < 4; ++rg) {
                const int i = i0 + rt * 16 + l4 * 4 + rg;
                #pragma unroll
                for (int n = 0; n < 4; ++n) {
                    const int j = cb + n * 16 + l15;
                    cacc[rt][n][rg] += bias_comb + mrow[i * 256 + j];
                }
            }
    }

    // ---- phase 3: softmax ----
    float rmax[4][4];
    #pragma unroll
    for (int rt = 0; rt < 4; ++rt)
        #pragma unroll
        for (int rg = 0; rg < 4; ++rg) {
            float mx = fmaxf(fmaxf(cacc[rt][0][rg], cacc[rt][1][rg]),
                             fmaxf(cacc[rt][2][rg], cacc[rt][3][rg]));
            mx = fmaxf(mx, __shfl_xor(mx, 1));
            mx = fmaxf(mx, __shfl_xor(mx, 2));
            mx = fmaxf(mx, __shfl_xor(mx, 4));
            mx = fmaxf(mx, __shfl_xor(mx, 8));
            rmax[rt][rg] = mx;
        }
    if (l15 == 0) {
        #pragma unroll
        for (int rt = 0; rt < 4; ++rt)
            #pragma unroll
            for (int rg = 0; rg < 4; ++rg)
                RED[(rt * 16 + l4 * 4 + rg) * 4 + w] = rmax[rt][rg];
    }
    __syncthreads();
    #pragma unroll
    for (int rt = 0; rt < 4; ++rt)
        #pragma unroll
        for (int rg = 0; rg < 4; ++rg) {
            const int row = rt * 16 + l4 * 4 + rg;
            rmax[rt][rg] = fmaxf(fmaxf(RED[row * 4 + 0], RED[row * 4 + 1]),
                                 fmaxf(RED[row * 4 + 2], RED[row * 4 + 3]));
        }
    __syncthreads();

    float rinv[4][4];
    #pragma unroll
    for (int rt = 0; rt < 4; ++rt)
        #pragma unroll
        for (int rg = 0; rg < 4; ++rg) {
            float sm = 0.f;
            #pragma unroll
            for (int n = 0; n < 4; ++n) {
                const float e = __expf(cacc[rt][n][rg] - rmax[rt][rg]);
                cacc[rt][n][rg] = e;
                sm += e;
            }
            sm += __shfl_xor(sm, 1);
            sm += __shfl_xor(sm, 2);
            sm += __shfl_xor(sm, 4);
            sm += __shfl_xor(sm, 8);
            rinv[rt][rg] = sm;
        }
    if (l15 == 0) {
        #pragma unroll
        for (int rt = 0; rt < 4; ++rt)
            #pragma unroll
            for (int rg = 0; rg < 4; ++rg)
                RED[(rt * 16 + l4 * 4 + rg) * 4 + w] = rinv[rt][rg];
    }
    __syncthreads();
    #pragma unroll
    for (int rt = 0; rt < 4; ++rt)
        #pragma unroll
        for (int rg = 0; rg < 4; ++rg) {
            const int row = rt * 16 + l4 * 4 + rg;
            const float tot = (RED[row * 4 + 0] + RED[row * 4 + 1])
                            + (RED[row * 4 + 2] + RED[row * 4 + 3]);
            rinv[rt][rg] = 1.f / tot;
        }
    __syncthreads();

    // ---- write P (bf16, swizzled) + build V^T (bf16, swizzled) ----
    #pragma unroll
    for (int rt = 0; rt < 4; ++rt)
        #pragma unroll
        for (int n = 0; n < 4; ++n)
            #pragma unroll
            for (int rg = 0; rg < 4; ++rg) {
                const int row = rt * 16 + l4 * 4 + rg;
                const int col = cb + n * 16 + l15;
                const int byt = (row * 512 + col * 2) ^ ((row & 7) << 4);
                *(short*)(PB + byt) = f2bf(cacc[rt][n][rg] * rinv[rt][rg]);
            }
    {
        const ushort* vb_h = vbuf + (size_t)head * S * DH;
        #pragma unroll
        for (int it = 0; it < 8; ++it) {
            const int idx = tid + it * 256;       // 0..2047
            const int t = idx >> 3, d0 = (idx & 7) * 8;
            const s16x8 v8 = *(const s16x8*)(vb_h + t * 64 + d0);
            #pragma unroll
            for (int c = 0; c < 8; ++c) {
                const int d = d0 + c;
                const int byt = (d * 512 + t * 2) ^ ((d & 7) << 4);
                *(short*)(VT + byt) = v8[c];
            }
        }
    }
    __syncthreads();

    // ---- phase 4: PV via MFMA ----
    f32x4 pacc[4];
    #pragma unroll
    for (int n = 0; n < 4; ++n) pacc[n] = (f32x4){0.f, 0.f, 0.f, 0.f};
    #pragma unroll
    for (int kk = 0; kk < 8; ++kk) {
        const int prow = w * 16 + l15;
        const int byta = (prow * 512 + kk * 64 + 16 * l4) ^ ((prow & 7) << 4);
        const s16x8 pa = *(const s16x8*)(PB + byta);
        #pragma unroll
        for (int n = 0; n < 4; ++n) {
            const int d = n * 16 + l15;
            const int bytb = (d * 512 + kk * 64 + 16 * l4) ^ ((d & 7) << 4);
            const s16x8 vb8 = *(const s16x8*)(VT + bytb);
            pacc[n] = __builtin_amdgcn_mfma_f32_16x16x32_bf16(pa, vb8, pacc[n], 0, 0, 0);
        }
    }
    #pragma unroll
    for (int n = 0; n < 4; ++n)
        #pragma unroll
        for (int rg = 0; rg < 4; ++rg) {
            const int i = i0 + w * 16 + l4 * 4 + rg;
            const int d = n * 16 + l15;
            attn[(((size_t)bb * S + i) * H + hh) * DH + d] = (ushort)f2bf(pacc[n][rg]);
        }
}

// ---------------------------------------------------------------------------
// launcher
// ---------------------------------------------------------------------------
extern "C" void kernel_launch(void* const* d_in, const int* in_sizes, int n_in,
                              void* d_out, int out_size, void* d_ws, size_t ws_size,
                              hipStream_t stream)
{
    (void)in_sizes; (void)n_in; (void)out_size; (void)ws_size;

    const float* x        = (const float*)d_in[0];
    const float* particles= (const float*)d_in[1];
    const float* wq       = (const float*)d_in[2];
    const float* wk       = (const float*)d_in[3];
    const float* wv       = (const float*)d_in[4];
    const float* dense_w  = (const float*)d_in[5];
    const float* dense_b  = (const float*)d_in[6];
    const float* c1k      = (const float*)d_in[7];
    const float* c1b      = (const float*)d_in[8];
    const float* c3k      = (const float*)d_in[9];
    const float* c3b      = (const float*)d_in[10];
    const float* c5k      = (const float*)d_in[11];
    const float* c5b      = (const float*)d_in[12];
    const float* mw1      = (const float*)d_in[13];
    const float* mb1      = (const float*)d_in[14];
    const float* mw2      = (const float*)d_in[15];
    const float* mb2      = (const float*)d_in[16];
    const float* mw3      = (const float*)d_in[17];
    const float* mb3      = (const float*)d_in[18];
    float* out = (float*)d_out;

    // workspace layout:
    //   xbf   16384*512 bf16      =  8,388,608 ush
    //   wt    4*512*512 bf16      =  1,048,576 ush
    //   qb/kb/vb (B,H,S,DH) bf16  =  8,388,608 ush each
    //   attnb 16384*512 bf16      =  8,388,608 ush
    //   mb    B*S*S f32           =  4,194,304 f32
    // total ~103 MB
    ushort* xbf   = (ushort*)d_ws;
    ushort* wt    = xbf   + (size_t)8388608;
    ushort* qb    = wt    + (size_t)1048576;
    ushort* kb    = qb    + (size_t)8388608;
    ushort* vb    = kb    + (size_t)8388608;
    ushort* attnb = vb    + (size_t)8388608;
    float*  mb    = (float*)(attnb + (size_t)8388608);

    convert_x_kernel<<<dim3(4096), 256, 0, stream>>>(x, xbf);
    transpose_w_kernel<<<dim3(16, 16, 4), 256, 0, stream>>>(wq, wk, wv, dense_w, wt);
    pairwise_mlp_kernel<<<dim3(B * S), 256, 0, stream>>>(particles, mw1, mb1, mw2, mb2, mw3, mb3, mb);

    gemm_mfma_kernel<0><<<dim3(4, 128, 3), 256, 0, stream>>>(
        xbf, wt, qb, kb, vb, nullptr, nullptr);

    fused_mfma_kernel<<<dim3(4, BH), 256, 0, stream>>>(
        qb, kb, vb, c1k, c1b, c3k, c3b, c5k, c5b, mb, attnb);

    gemm_mfma_kernel<1><<<dim3(4, 128, 1), 256, 0, stream>>>(
        attnb, wt + (size_t)3 * DD * DD, nullptr, nullptr, nullptr, dense_b, out);
}